// Round 1
// baseline (116.309 us; speedup 1.0000x reference)
//
#include <hip/hip_runtime.h>
#include <math.h>

// Problem constants (StructureLoss: B=32, C=1, H=W=512, 31x31 box filter, pad 15)
#define BB 32
#define HH 512
#define WW 512
#define KK 31
#define PP 15
#define HSEG 16                       // rows per block segment
#define BLOCKS_PER_IMG (HH / HSEG)    // 32
#define NBLOCKS (BB * BLOCKS_PER_IMG) // 1024
#define NTHREADS 256                  // 2 columns per thread
#define HALO 16                       // LDS halo (>= PP, kept 16 for 8B alignment)

__device__ inline float wave_reduce(float v) {
    #pragma unroll
    for (int off = 32; off > 0; off >>= 1) v += __shfl_down(v, off);
    return v;
}

__device__ inline void accum_px(float s, float tg, float x,
                                float& aw, float& ab, float& ai, float& au) {
    const float inv = 1.0f / (float)(KK * KK);
    float pooled = s * inv;
    float weit = fmaf(5.0f, fabsf(pooled - tg), 1.0f);
    // stable BCE-with-logits, elementwise
    float bce = fmaxf(x, 0.0f) - x * tg + __logf(1.0f + __expf(-fabsf(x)));
    float p = 1.0f / (1.0f + __expf(-x));
    aw += weit;
    ab += weit * bce;
    ai += p * tg * weit;
    au += (p + tg) * weit;
}

__global__ __launch_bounds__(NTHREADS) void structure_loss_main(
    const float* __restrict__ pred, const float* __restrict__ target,
    float* __restrict__ partials /* [NBLOCKS][4] */)
{
    __shared__ float svs[WW + 2 * HALO];   // one row of vertical sums + zero halos
    __shared__ float red[4 * 4];           // [wave][quantity]

    const int t   = threadIdx.x;
    const int blk = blockIdx.x;
    const int b   = blk / BLOCKS_PER_IMG;
    const int seg = blk % BLOCKS_PER_IMG;
    const int h0  = seg * HSEG;
    const int c0  = 2 * t;

    const float* tb = target + (size_t)b * HH * WW;
    const float* pb = pred   + (size_t)b * HH * WW;

    // zero the horizontal halos once (never overwritten)
    if (t < HALO) { svs[t] = 0.0f; svs[HALO + WW + t] = 0.0f; }

    // initial vertical window for output row h0: rows [h0-PP, h0+PP] clipped
    float vs0 = 0.0f, vs1 = 0.0f;
    {
        int ylo = h0 - PP; if (ylo < 0) ylo = 0;
        int yhi = h0 + PP; if (yhi > HH - 1) yhi = HH - 1;
        for (int y = ylo; y <= yhi; ++y) {
            float2 v = *(const float2*)(tb + (size_t)y * WW + c0);
            vs0 += v.x; vs1 += v.y;
        }
    }

    float aw = 0.0f, ab = 0.0f, ai = 0.0f, au = 0.0f;

    for (int h = h0; h < h0 + HSEG; ++h) {
        __syncthreads();                 // previous row's reads done before overwrite
        svs[HALO + c0]     = vs0;
        svs[HALO + c0 + 1] = vs1;
        __syncthreads();

        // horizontal 31-tap sums for cols c0, c0+1
        float s0 = 0.0f;
        #pragma unroll
        for (int j = -PP; j <= PP; ++j) s0 += svs[HALO + c0 + j];
        float s1 = s0 - svs[HALO + c0 - PP] + svs[HALO + c0 + 1 + PP];

        float2 tg = *(const float2*)(tb + (size_t)h * WW + c0);
        float2 pr = *(const float2*)(pb + (size_t)h * WW + c0);
        accum_px(s0, tg.x, pr.x, aw, ab, ai, au);
        accum_px(s1, tg.y, pr.y, aw, ab, ai, au);

        // slide vertical window to output row h+1: window rows [h-PP+1, h+PP+1]
        int yadd = h + PP + 1;
        int ysub = h - PP;
        if (yadd < HH) {
            float2 v = *(const float2*)(tb + (size_t)yadd * WW + c0);
            vs0 += v.x; vs1 += v.y;
        }
        if (ysub >= 0) {
            float2 v = *(const float2*)(tb + (size_t)ysub * WW + c0);
            vs0 -= v.x; vs1 -= v.y;
        }
    }

    // block reduction: wave shuffle, then across the 4 waves via LDS
    aw = wave_reduce(aw);
    ab = wave_reduce(ab);
    ai = wave_reduce(ai);
    au = wave_reduce(au);

    const int wave = t >> 6;
    const int lane = t & 63;
    __syncthreads();   // svs no longer needed; protect red[] usage pattern
    if (lane == 0) {
        red[wave * 4 + 0] = aw;
        red[wave * 4 + 1] = ab;
        red[wave * 4 + 2] = ai;
        red[wave * 4 + 3] = au;
    }
    __syncthreads();
    if (t == 0) {
        float w = 0.0f, bc = 0.0f, in = 0.0f, un = 0.0f;
        #pragma unroll
        for (int i = 0; i < 4; ++i) {
            w  += red[i * 4 + 0];
            bc += red[i * 4 + 1];
            in += red[i * 4 + 2];
            un += red[i * 4 + 3];
        }
        float* o = partials + (size_t)blk * 4;
        o[0] = w; o[1] = bc; o[2] = in; o[3] = un;
    }
}

__global__ __launch_bounds__(64) void structure_loss_finalize(
    const float* __restrict__ partials, float* __restrict__ out)
{
    const int b = threadIdx.x;
    float val = 0.0f;
    if (b < BB) {
        float w = 0.0f, bc = 0.0f, in = 0.0f, un = 0.0f;
        for (int i = 0; i < BLOCKS_PER_IMG; ++i) {
            const float* p = partials + ((size_t)(b * BLOCKS_PER_IMG + i)) * 4;
            w  += p[0];
            bc += p[1];
            in += p[2];
            un += p[3];
        }
        float wbce = bc / w;
        float wiou = 1.0f - (in + 1.0f) / (un - in + 1.0f);
        val = wbce + wiou;
    }
    val = wave_reduce(val);
    if (b == 0) out[0] = val / (float)BB;
}

extern "C" void kernel_launch(void* const* d_in, const int* in_sizes, int n_in,
                              void* d_out, int out_size, void* d_ws, size_t ws_size,
                              hipStream_t stream) {
    const float* pred   = (const float*)d_in[0];
    const float* target = (const float*)d_in[1];
    float* out      = (float*)d_out;
    float* partials = (float*)d_ws;   // NBLOCKS*4 floats = 16 KB

    structure_loss_main<<<NBLOCKS, NTHREADS, 0, stream>>>(pred, target, partials);
    structure_loss_finalize<<<1, 64, 0, stream>>>(partials, out);
}